// Round 4
// baseline (257.947 us; speedup 1.0000x reference)
//
#include <hip/hip_runtime.h>

// MHA forward: x[4096,1024] fp32, W{q,k,v,o}[1024,1024] fp32 -> out[4096,1024] fp32
// cvt->bf16 + rope-table | fused QKV gemm w/ rope epilogue (head-major out) |
// flash attn (swapped-QK^T, 2-phase single-barrier pipeline, 1024 blocks) | O-proj

typedef __attribute__((ext_vector_type(4))) float f32x4;
typedef __attribute__((ext_vector_type(8))) short short8;
typedef __attribute__((ext_vector_type(2))) unsigned int u32x2;
typedef unsigned short u16;

#define SEQ 4096
#define DIMM 1024
#define NH 16
#define HD 64

__device__ __forceinline__ u16 f2b(float f) {
  unsigned u = __float_as_uint(f);
  u += 0x7FFFu + ((u >> 16) & 1u);
  return (u16)(u >> 16);
}
__device__ __forceinline__ f32x4 mfma16(short8 a, short8 b, f32x4 c) {
  return __builtin_amdgcn_mfma_f32_16x16x32_bf16(a, b, c, 0, 0, 0);
}
#define GLL16(gp, lp)                                                        \
  __builtin_amdgcn_global_load_lds(                                          \
      (const __attribute__((address_space(1))) unsigned int*)(gp),           \
      (__attribute__((address_space(3))) unsigned int*)(lp), 16, 0, 0)

// ---------------- convert x + 4 weights to bf16; build rope table ---------------
// tab[s*64+d] = (cos(s*inv_{d>>1}), (d&1 ? +sin : -sin))
__global__ __launch_bounds__(256) void cvt_all(
    const float* __restrict__ x, const float* __restrict__ wq,
    const float* __restrict__ wk, const float* __restrict__ wv,
    const float* __restrict__ wo,
    u16* __restrict__ xb, u16* __restrict__ wqb, u16* __restrict__ wkb,
    u16* __restrict__ wvb, u16* __restrict__ wob, float2* __restrict__ tab) {
  int i = blockIdx.x * 256 + threadIdx.x;
  if (i < 2097152) {
    const float* src;
    u16* dst;
    int j;
    if (i < 1048576) {
      src = x; dst = xb; j = i;
    } else {
      int t = i - 1048576;
      int wsel = t >> 18;
      j = t & 262143;
      src = (wsel == 0) ? wq : (wsel == 1) ? wk : (wsel == 2) ? wv : wo;
      dst = (wsel == 0) ? wqb : (wsel == 1) ? wkb : (wsel == 2) ? wvb : wob;
    }
    float4 v = ((const float4*)src)[j];
    ushort4 o;
    o.x = f2b(v.x); o.y = f2b(v.y); o.z = f2b(v.z); o.w = f2b(v.w);
    ((ushort4*)dst)[j] = o;
  } else {
    int j = i - 2097152;  // 0..262143 = 4096*64
    int s = j >> 6, d = j & 63, fi = d >> 1;
    float ang = (float)s * powf(10000.0f, -(float)fi * (1.0f / 32.0f));
    float sn, cs;
    sincosf(ang, &sn, &cs);
    tab[j] = make_float2(cs, (d & 1) ? sn : -sn);
  }
}

// ---------------- GEMM: C = A[M,K] * B[N,K]^T, 2-phase dbuf ---------------------
// MODE 0: fp32 C[M,N].  MODE 1: QKV: rope (Q scaled 1/8) + head-major bf16 scatter.
template <int MODE>
__global__ __launch_bounds__(256) void gemm_bt(
    const u16* __restrict__ A, const u16* __restrict__ B, float* __restrict__ C,
    const float2* __restrict__ tab, u16* __restrict__ Qh, u16* __restrict__ Kh,
    u16* __restrict__ Vh, int K, int N) {
  __shared__ __align__(16) u16 As[2][4096];
  __shared__ __align__(16) u16 Bs[2][4096];
  const int tid = threadIdx.x;
  const int bm = blockIdx.x, bn = blockIdx.y;
  const int w = tid >> 6, lane = tid & 63;
  const int wm = w >> 1, wn = w & 1;
  const int l15 = lane & 15, g = lane >> 4;

  f32x4 acc[4][4] = {};

  const u16* Ap0 = A + (size_t)(bm * 128 + (tid >> 2)) * K + (tid & 3) * 8;
  const u16* Ap1 = Ap0 + (size_t)64 * K;
  const u16* Bp0 = B + (size_t)(bn * 128 + (tid >> 2)) * K + (tid & 3) * 8;
  const u16* Bp1 = Bp0 + (size_t)64 * K;

  // prologue: stage k=0 into buf 0
  GLL16(Ap0, &As[0][w * 512]);
  GLL16(Ap1, &As[0][2048 + w * 512]);
  GLL16(Bp0, &Bs[0][w * 512]);
  GLL16(Bp1, &Bs[0][2048 + w * 512]);
  __syncthreads();

  const int nk = K >> 5;
  for (int t = 0; t < nk; ++t) {
    const int cur = t & 1;
    if (t + 1 < nk) {  // prefetch next K-step into other buffer
      const int k1 = (t + 1) * 32;
      GLL16(Ap0 + k1, &As[cur ^ 1][w * 512]);
      GLL16(Ap1 + k1, &As[cur ^ 1][2048 + w * 512]);
      GLL16(Bp0 + k1, &Bs[cur ^ 1][w * 512]);
      GLL16(Bp1 + k1, &Bs[cur ^ 1][2048 + w * 512]);
    }
    short8 af[4], bf[4];
#pragma unroll
    for (int m = 0; m < 4; ++m)
      af[m] = *(const short8*)&As[cur][(wm * 64 + m * 16 + l15) * 32 + g * 8];
#pragma unroll
    for (int n = 0; n < 4; ++n)
      bf[n] = *(const short8*)&Bs[cur][(wn * 64 + n * 16 + l15) * 32 + g * 8];
#pragma unroll
    for (int m = 0; m < 4; ++m)
#pragma unroll
      for (int n = 0; n < 4; ++n)
        acc[m][n] = mfma16(af[m], bf[n], acc[m][n]);
    __syncthreads();  // drains this iter's prefetch; frees buf[cur] for next GLL
  }

  if (MODE == 0) {
#pragma unroll
    for (int m = 0; m < 4; ++m) {
      int grow = bm * 128 + wm * 64 + m * 16 + g * 4;
#pragma unroll
      for (int n = 0; n < 4; ++n) {
        int gcol = bn * 128 + wn * 64 + n * 16 + l15;
#pragma unroll
        for (int r = 0; r < 4; ++r)
          C[(size_t)(grow + r) * N + gcol] = acc[m][n][r];
      }
    }
  } else {
    // bn 0..7 -> Q (rope, x0.125), 8..15 -> K (rope), 16..23 -> V (copy)
    const int sector = bn >> 3;
    const int hh = (bn & 7) * 2 + wn;
    u16* dst = (sector == 0) ? Qh : (sector == 1) ? Kh : Vh;
    const float qs = (sector == 0) ? 0.125f : 1.0f;
#pragma unroll
    for (int m = 0; m < 4; ++m) {
#pragma unroll
      for (int n = 0; n < 4; ++n) {
        const int d = n * 16 + l15;
#pragma unroll
        for (int r = 0; r < 4; ++r) {
          const int srow = bm * 128 + wm * 64 + m * 16 + g * 4 + r;
          float v = acc[m][n][r];
          float val;
          if (sector < 2) {
            float p = __shfl_xor(v, 1);
            float2 tc = tab[srow * 64 + d];
            val = (v * tc.x + p * tc.y) * qs;
          } else {
            val = v;
          }
          float valn = __shfl_xor(val, 1);
          if (!(l15 & 1)) {
            unsigned pk;
            asm("v_cvt_pk_bf16_f32 %0, %1, %2" : "=v"(pk) : "v"(val), "v"(valn));
            *(unsigned*)&dst[((size_t)hh * SEQ + srow) * HD + d] = pk;
          }
        }
      }
    }
  }
}

// ---------------- causal flash attention ----------------------------------------
// 1024 blocks; xcd=L&7 hosts heads {xcd,xcd+8}; c' -> c pairs heavy+light per CU
// (130 tiles/CU). Block = 4 waves x 16 q-rows = 64-q chunk, KVBLK=64.
// 2-phase pipeline, ONE __syncthreads per tile. Swapped QK^T, in-reg softmax.
__global__ __launch_bounds__(256, 4) void attn_fwd(
    const u16* __restrict__ Qh, const u16* __restrict__ Kh,
    const u16* __restrict__ Vh, u16* __restrict__ Ob) {
  __shared__ __align__(16) u16 Ks[2][64 * 64];   // [kv][d], chunk^=(row&7)
  __shared__ __align__(16) u16 Vt[2][64 * 64];   // [d][kv], chunk^=((d^(d>>3))&7)
  __shared__ __align__(16) u16 Ps[4][16 * 64];   // per-wave [q][kv], chunk^=(q&7)

  const int L = blockIdx.x;
  const int xcd = L & 7, sl = L >> 3;            // sl 0..127
  const int h = xcd + 8 * (sl >> 6);
  const int cp = sl & 63;
  const int c = (cp < 32) ? (63 - 2 * cp) : (2 * (cp - 32));

  const int tid = threadIdx.x, w = tid >> 6, lane = tid & 63;
  const int l15 = lane & 15, g = lane >> 4;
  const int qr0 = c * 64 + w * 16;
  const size_t hS = (size_t)h * SEQ;

  // K staging geometry (GLL, pre-swizzled global source)
  const int krow0 = w * 8 + (lane >> 3);
  const int kc0 = ((lane & 7) ^ (krow0 & 7)) * 8;
  const int krow1 = 32 + krow0;
  const int kc1 = ((lane & 7) ^ (krow1 & 7)) * 8;
  // V transpose staging geometry
  const int kvp = tid >> 3, d0 = (tid & 7) * 8;
  const u16* Vsrc = Vh + (hS + kvp * 2) * HD + d0;
  int voff[8];
#pragma unroll
  for (int j = 0; j < 8; ++j) {
    int d = d0 + j;
    int sw = (d ^ (d >> 3)) & 7;
    voff[j] = d * 64 + (((kvp >> 2) ^ sw) << 3) + (kvp & 3) * 2;
  }

  const u16* Qp = Qh + (hS + qr0 + l15) * HD + g * 8;
  short8 qf0 = *(const short8*)(Qp);
  short8 qf1 = *(const short8*)(Qp + 32);

  f32x4 o[4] = {};
  float m_ = -3.0e38f, lg = 0.f;

  // prologue: stage tile 0
  GLL16(Kh + (hS + krow0) * HD + kc0, &Ks[0][w * 512]);
  GLL16(Kh + (hS + krow1) * HD + kc1, &Ks[0][2048 + w * 512]);
  short8 va = *(const short8*)(Vsrc);
  short8 vb = *(const short8*)(Vsrc + HD);

  for (int t = 0; t <= c; ++t) {
    const int cur = t & 1;
    // A: write V(t) into Vt[cur] (va/vb register dep drains prior vmem)
    {
      u16* vtb = &Vt[cur][0];
#pragma unroll
      for (int j = 0; j < 8; ++j) {
        ushort2 pr;
        pr.x = (u16)va[j];
        pr.y = (u16)vb[j];
        *(ushort2*)(vtb + voff[j]) = pr;
      }
    }
    // B: the one barrier (drains each wave's GLL + makes Vt[cur] visible)
    __syncthreads();
    // C: prefetch tile t+1 (flies during D)
    if (t < c) {
      const size_t kb_ = hS + (size_t)(t + 1) * 64;
      GLL16(Kh + (kb_ + krow0) * HD + kc0, &Ks[cur ^ 1][w * 512]);
      GLL16(Kh + (kb_ + krow1) * HD + kc1, &Ks[cur ^ 1][2048 + w * 512]);
      va = *(const short8*)(Vsrc + (size_t)(t + 1) * 64 * HD);
      vb = *(const short8*)(Vsrc + (size_t)(t + 1) * 64 * HD + HD);
    }
    // D: compute tile t
    f32x4 s[4] = {};
#pragma unroll
    for (int kb = 0; kb < 4; ++kb) {
      int row = kb * 16 + l15;
      short8 k0 = *(const short8*)&Ks[cur][row * 64 + ((g ^ (row & 7)) << 3)];
      short8 k1 = *(const short8*)&Ks[cur][row * 64 + (((4 + g) ^ (row & 7)) << 3)];
      s[kb] = mfma16(k0, qf0, s[kb]);
      s[kb] = mfma16(k1, qf1, s[kb]);
    }
    if (t == c) {  // diagonal: causal mask (q = l15 col, kv = row)
      const int kv0 = t * 64;
      int q = qr0 + l15;
#pragma unroll
      for (int kb = 0; kb < 4; ++kb) {
        int kvb = kv0 + kb * 16 + g * 4;
#pragma unroll
        for (int r = 0; r < 4; ++r)
          if (kvb + r > q) s[kb][r] = -1.0e30f;
      }
    }
    // in-register online softmax (q = l15, kv register-local)
    float mx = fmaxf(fmaxf(fmaxf(s[0][0], s[0][1]), fmaxf(s[0][2], s[0][3])),
                     fmaxf(fmaxf(fmaxf(s[1][0], s[1][1]), fmaxf(s[1][2], s[1][3])),
                           fmaxf(fmaxf(fmaxf(s[2][0], s[2][1]), fmaxf(s[2][2], s[2][3])),
                                 fmaxf(fmaxf(s[3][0], s[3][1]), fmaxf(s[3][2], s[3][3])))));
    mx = fmaxf(mx, __shfl_xor(mx, 16));
    mx = fmaxf(mx, __shfl_xor(mx, 32));
    if (!__all(mx - m_ <= 8.0f)) {  // defer-max
      float nm = fmaxf(m_, mx);
      float sc = __expf(m_ - nm);
      m_ = nm;
      lg *= sc;
#pragma unroll
      for (int r = 0; r < 4; ++r) {
        float so = __shfl(sc, g * 4 + r);
        o[0][r] *= so; o[1][r] *= so; o[2][r] *= so; o[3][r] *= so;
      }
    }
    // P = exp(S - m) -> bf16 -> per-wave LDS tile
    {
      float ps = 0.f;
#pragma unroll
      for (int kb = 0; kb < 4; ++kb) {
        float p0 = __expf(s[kb][0] - m_);
        float p1 = __expf(s[kb][1] - m_);
        float p2 = __expf(s[kb][2] - m_);
        float p3 = __expf(s[kb][3] - m_);
        ps += (p0 + p1) + (p2 + p3);
        unsigned w0, w1;
        asm("v_cvt_pk_bf16_f32 %0, %1, %2" : "=v"(w0) : "v"(p0), "v"(p1));
        asm("v_cvt_pk_bf16_f32 %0, %1, %2" : "=v"(w1) : "v"(p2), "v"(p3));
        int ch = (kb * 2 + (g >> 1)) ^ (l15 & 7);
        *(u32x2*)&Ps[w][l15 * 64 + ch * 8 + (g & 1) * 4] = (u32x2){w0, w1};
      }
      lg += ps;
    }
    // PV: O[16q][64d] += P * V
    short8 pa0 = *(const short8*)&Ps[w][l15 * 64 + ((g ^ (l15 & 7)) << 3)];
    short8 pa1 = *(const short8*)&Ps[w][l15 * 64 + (((4 + g) ^ (l15 & 7)) << 3)];
#pragma unroll
    for (int nb = 0; nb < 4; ++nb) {
      int rv = nb * 16 + l15;
      int swv = (rv ^ (rv >> 3)) & 7;
      short8 v0f = *(const short8*)&Vt[cur][rv * 64 + ((g ^ swv) << 3)];
      short8 v1f = *(const short8*)&Vt[cur][rv * 64 + (((4 + g) ^ swv) << 3)];
      o[nb] = mfma16(pa0, v0f, o[nb]);
      o[nb] = mfma16(pa1, v1f, o[nb]);
    }
  }

  // epilogue
  float l = lg;
  l += __shfl_xor(l, 16);
  l += __shfl_xor(l, 32);
  float il = 1.0f / l;
#pragma unroll
  for (int r = 0; r < 4; ++r) {
    float ilr = __shfl(il, g * 4 + r);
    int qrow = qr0 + g * 4 + r;
#pragma unroll
    for (int nb = 0; nb < 4; ++nb)
      Ob[(size_t)qrow * DIMM + h * HD + nb * 16 + l15] = f2b(o[nb][r] * ilr);
  }
}

// ---------------- workspace layout (bytes) --------------------------------------
#define OFF_XB 0u           // 8MB
#define OFF_WQKV 8388608u   // 6MB (wq,wk,wv bf16 contiguous)
#define OFF_WOB 14680064u   // 2MB
#define OFF_TAB 16777216u   // 2MB (float2[4096*64])
#define OFF_QH 18874368u    // 8MB
#define OFF_KH 27262976u    // 8MB
#define OFF_VH 35651584u    // 8MB
#define OFF_OB 44040192u    // 8MB -> end 50.3MB

extern "C" void kernel_launch(void* const* d_in, const int* in_sizes, int n_in,
                              void* d_out, int out_size, void* d_ws, size_t ws_size,
                              hipStream_t stream) {
  const float* x = (const float*)d_in[0];
  const float* Wq = (const float*)d_in[1];
  const float* Wk = (const float*)d_in[2];
  const float* Wv = (const float*)d_in[3];
  const float* Wo = (const float*)d_in[4];
  float* out = (float*)d_out;
  char* ws = (char*)d_ws;

  u16* xb = (u16*)(ws + OFF_XB);
  u16* wqkv = (u16*)(ws + OFF_WQKV);
  u16* wqb = wqkv;
  u16* wkb = wqkv + (size_t)DIMM * DIMM;
  u16* wvb = wqkv + (size_t)2 * DIMM * DIMM;
  u16* wob = (u16*)(ws + OFF_WOB);
  float2* tab = (float2*)(ws + OFF_TAB);
  u16* Qh = (u16*)(ws + OFF_QH);
  u16* Kh = (u16*)(ws + OFF_KH);
  u16* Vh = (u16*)(ws + OFF_VH);
  u16* Ob = (u16*)(ws + OFF_OB);

  cvt_all<<<9216, 256, 0, stream>>>(x, Wq, Wk, Wv, Wo, xb, wqb, wkb, wvb, wob, tab);

  // fused QKV projection + rope + head-major scatter
  gemm_bt<1><<<dim3(SEQ / 128, 3072 / 128), 256, 0, stream>>>(
      xb, wqkv, nullptr, tab, Qh, Kh, Vh, DIMM, 3072);

  attn_fwd<<<1024, 256, 0, stream>>>(Qh, Kh, Vh, Ob);

  gemm_bt<0><<<dim3(SEQ / 128, DIMM / 128), 256, 0, stream>>>(
      Ob, wob, out, nullptr, nullptr, nullptr, nullptr, DIMM, DIMM);
}

// Round 5
// 257.215 us; speedup vs baseline: 1.0028x; 1.0028x over previous
//
#include <hip/hip_runtime.h>

// MHA forward: x[4096,1024] fp32, W{q,k,v,o}[1024,1024] fp32 -> out[4096,1024] fp32
// cvt->bf16 + rope-table | fused QKV gemm w/ rope epilogue (ring-3 counted-vmcnt
// pipeline) | flash attn (swapped-QK^T, descending-c dispatch, setprio) | O-proj

typedef __attribute__((ext_vector_type(4))) float f32x4;
typedef __attribute__((ext_vector_type(8))) short short8;
typedef __attribute__((ext_vector_type(2))) unsigned int u32x2;
typedef unsigned short u16;

#define SEQ 4096
#define DIMM 1024
#define NH 16
#define HD 64

__device__ __forceinline__ u16 f2b(float f) {
  unsigned u = __float_as_uint(f);
  u += 0x7FFFu + ((u >> 16) & 1u);
  return (u16)(u >> 16);
}
__device__ __forceinline__ f32x4 mfma16(short8 a, short8 b, f32x4 c) {
  return __builtin_amdgcn_mfma_f32_16x16x32_bf16(a, b, c, 0, 0, 0);
}
#define GLL16(gp, lp)                                                        \
  __builtin_amdgcn_global_load_lds(                                          \
      (const __attribute__((address_space(1))) unsigned int*)(gp),           \
      (__attribute__((address_space(3))) unsigned int*)(lp), 16, 0, 0)

// ---------------- convert x + 4 weights to bf16; build rope table ---------------
__global__ __launch_bounds__(256) void cvt_all(
    const float* __restrict__ x, const float* __restrict__ wq,
    const float* __restrict__ wk, const float* __restrict__ wv,
    const float* __restrict__ wo,
    u16* __restrict__ xb, u16* __restrict__ wqb, u16* __restrict__ wkb,
    u16* __restrict__ wvb, u16* __restrict__ wob, float2* __restrict__ tab) {
  int i = blockIdx.x * 256 + threadIdx.x;
  if (i < 2097152) {
    const float* src;
    u16* dst;
    int j;
    if (i < 1048576) {
      src = x; dst = xb; j = i;
    } else {
      int t = i - 1048576;
      int wsel = t >> 18;
      j = t & 262143;
      src = (wsel == 0) ? wq : (wsel == 1) ? wk : (wsel == 2) ? wv : wo;
      dst = (wsel == 0) ? wqb : (wsel == 1) ? wkb : (wsel == 2) ? wvb : wob;
    }
    float4 v = ((const float4*)src)[j];
    ushort4 o;
    o.x = f2b(v.x); o.y = f2b(v.y); o.z = f2b(v.z); o.w = f2b(v.w);
    ((ushort4*)dst)[j] = o;
  } else {
    int j = i - 2097152;  // 0..262143 = 4096*64
    int s = j >> 6, d = j & 63, fi = d >> 1;
    float ang = (float)s * powf(10000.0f, -(float)fi * (1.0f / 32.0f));
    float sn, cs;
    sincosf(ang, &sn, &cs);
    tab[j] = make_float2(cs, (d & 1) ? sn : -sn);
  }
}

// ---------------- GEMM: C = A[M,K] * B[N,K]^T, ring-3 counted-vmcnt -------------
// MODE 0: fp32 C[M,N].  MODE 1: QKV: rope (Q scaled 1/8) + head-major bf16 scatter.
template <int MODE>
__global__ __launch_bounds__(256) void gemm_bt(
    const u16* __restrict__ A, const u16* __restrict__ B, float* __restrict__ C,
    const float2* __restrict__ tab, u16* __restrict__ Qh, u16* __restrict__ Kh,
    u16* __restrict__ Vh, int K, int N) {
  __shared__ __align__(16) u16 As[3][4096];
  __shared__ __align__(16) u16 Bs[3][4096];
  const int tid = threadIdx.x;
  const int bm = blockIdx.x, bn = blockIdx.y;
  const int w = tid >> 6, lane = tid & 63;
  const int wm = w >> 1, wn = w & 1;
  const int l15 = lane & 15, g = lane >> 4;

  f32x4 acc[4][4] = {};

  const u16* Ap0 = A + (size_t)(bm * 128 + (tid >> 2)) * K + (tid & 3) * 8;
  const u16* Ap1 = Ap0 + (size_t)64 * K;
  const u16* Bp0 = B + (size_t)(bn * 128 + (tid >> 2)) * K + (tid & 3) * 8;
  const u16* Bp1 = Bp0 + (size_t)64 * K;

  // prologue: stage tiles 0,1 (4 GLL each per wave)
  GLL16(Ap0, &As[0][w * 512]);
  GLL16(Ap1, &As[0][2048 + w * 512]);
  GLL16(Bp0, &Bs[0][w * 512]);
  GLL16(Bp1, &Bs[0][2048 + w * 512]);
  GLL16(Ap0 + 32, &As[1][w * 512]);
  GLL16(Ap1 + 32, &As[1][2048 + w * 512]);
  GLL16(Bp0 + 32, &Bs[1][w * 512]);
  GLL16(Bp1 + 32, &Bs[1][2048 + w * 512]);

  const int nk = K >> 5;
  int cur = 0;
  for (int t = 0; t < nk; ++t) {
    // tile t's 4 GLLs are the oldest; t+1's 4 may remain in flight
    if (t + 1 < nk)
      asm volatile("s_waitcnt vmcnt(4)" ::: "memory");
    else
      asm volatile("s_waitcnt vmcnt(0)" ::: "memory");
    __builtin_amdgcn_s_barrier();
    asm volatile("" ::: "memory");
    if (t + 2 < nk) {  // prefetch 2 ahead into the buffer everyone just vacated
      const int k2 = (t + 2) * 32;
      const int nb = (t + 2) % 3;
      GLL16(Ap0 + k2, &As[nb][w * 512]);
      GLL16(Ap1 + k2, &As[nb][2048 + w * 512]);
      GLL16(Bp0 + k2, &Bs[nb][w * 512]);
      GLL16(Bp1 + k2, &Bs[nb][2048 + w * 512]);
    }
    short8 af[4], bf[4];
#pragma unroll
    for (int m = 0; m < 4; ++m)
      af[m] = *(const short8*)&As[cur][(wm * 64 + m * 16 + l15) * 32 + g * 8];
#pragma unroll
    for (int n = 0; n < 4; ++n)
      bf[n] = *(const short8*)&Bs[cur][(wn * 64 + n * 16 + l15) * 32 + g * 8];
#pragma unroll
    for (int m = 0; m < 4; ++m)
#pragma unroll
      for (int n = 0; n < 4; ++n)
        acc[m][n] = mfma16(af[m], bf[n], acc[m][n]);
    cur = (cur == 2) ? 0 : cur + 1;
  }

  if (MODE == 0) {
#pragma unroll
    for (int m = 0; m < 4; ++m) {
      int grow = bm * 128 + wm * 64 + m * 16 + g * 4;
#pragma unroll
      for (int n = 0; n < 4; ++n) {
        int gcol = bn * 128 + wn * 64 + n * 16 + l15;
#pragma unroll
        for (int r = 0; r < 4; ++r)
          C[(size_t)(grow + r) * N + gcol] = acc[m][n][r];
      }
    }
  } else {
    // bn 0..7 -> Q (rope, x0.125), 8..15 -> K (rope), 16..23 -> V (copy)
    const int sector = bn >> 3;
    const int hh = (bn & 7) * 2 + wn;
    u16* dst = (sector == 0) ? Qh : (sector == 1) ? Kh : Vh;
    const float qs = (sector == 0) ? 0.125f : 1.0f;
#pragma unroll
    for (int m = 0; m < 4; ++m) {
#pragma unroll
      for (int n = 0; n < 4; ++n) {
        const int d = n * 16 + l15;
#pragma unroll
        for (int r = 0; r < 4; ++r) {
          const int srow = bm * 128 + wm * 64 + m * 16 + g * 4 + r;
          float v = acc[m][n][r];
          float val;
          if (sector < 2) {
            float p = __shfl_xor(v, 1);
            float2 tc = tab[srow * 64 + d];
            val = (v * tc.x + p * tc.y) * qs;
          } else {
            val = v;
          }
          float valn = __shfl_xor(val, 1);
          if (!(l15 & 1)) {
            unsigned pk;
            asm("v_cvt_pk_bf16_f32 %0, %1, %2" : "=v"(pk) : "v"(val), "v"(valn));
            *(unsigned*)&dst[((size_t)hh * SEQ + srow) * HD + d] = pk;
          }
        }
      }
    }
  }
}

// ---------------- causal flash attention ----------------------------------------
// 1024 blocks, DESCENDING chunk length: h = L&15 (pins head h to XCD h%8),
// c = 63-(L>>4). Heavy blocks dispatch first -> backfill keeps ~4 blocks/CU
// resident. Block = 4 waves x 16 q-rows = 64-q chunk, KVBLK=64, 2-phase pipeline,
// one barrier/tile. Swapped QK^T, in-reg softmax, setprio around MFMA.
__global__ __launch_bounds__(256, 4) void attn_fwd(
    const u16* __restrict__ Qh, const u16* __restrict__ Kh,
    const u16* __restrict__ Vh, u16* __restrict__ Ob) {
  __shared__ __align__(16) u16 Ks[2][64 * 64];   // [kv][d], chunk^=(row&7)
  __shared__ __align__(16) u16 Vt[2][64 * 64];   // [d][kv], chunk^=((d^(d>>3))&7)
  __shared__ __align__(16) u16 Ps[4][16 * 64];   // per-wave [q][kv], chunk^=(q&7)

  const int L = blockIdx.x;
  const int h = L & 15;
  const int c = 63 - (L >> 4);

  const int tid = threadIdx.x, w = tid >> 6, lane = tid & 63;
  const int l15 = lane & 15, g = lane >> 4;
  const int qr0 = c * 64 + w * 16;
  const size_t hS = (size_t)h * SEQ;

  const int krow0 = w * 8 + (lane >> 3);
  const int kc0 = ((lane & 7) ^ (krow0 & 7)) * 8;
  const int krow1 = 32 + krow0;
  const int kc1 = ((lane & 7) ^ (krow1 & 7)) * 8;
  const int kvp = tid >> 3, d0 = (tid & 7) * 8;
  const u16* Vsrc = Vh + (hS + kvp * 2) * HD + d0;
  int voff[8];
#pragma unroll
  for (int j = 0; j < 8; ++j) {
    int d = d0 + j;
    int sw = (d ^ (d >> 3)) & 7;
    voff[j] = d * 64 + (((kvp >> 2) ^ sw) << 3) + (kvp & 3) * 2;
  }

  const u16* Qp = Qh + (hS + qr0 + l15) * HD + g * 8;
  short8 qf0 = *(const short8*)(Qp);
  short8 qf1 = *(const short8*)(Qp + 32);

  f32x4 o[4] = {};
  float m_ = -3.0e38f, lg = 0.f;

  // prologue: stage tile 0
  GLL16(Kh + (hS + krow0) * HD + kc0, &Ks[0][w * 512]);
  GLL16(Kh + (hS + krow1) * HD + kc1, &Ks[0][2048 + w * 512]);
  short8 va = *(const short8*)(Vsrc);
  short8 vb = *(const short8*)(Vsrc + HD);

  for (int t = 0; t <= c; ++t) {
    const int cur = t & 1;
    // A: write V(t) into Vt[cur] (va/vb register dep drains prior vmem)
    {
      u16* vtb = &Vt[cur][0];
#pragma unroll
      for (int j = 0; j < 8; ++j) {
        ushort2 pr;
        pr.x = (u16)va[j];
        pr.y = (u16)vb[j];
        *(ushort2*)(vtb + voff[j]) = pr;
      }
    }
    // B: the one barrier (drains each wave's GLL + makes Vt[cur] visible)
    __syncthreads();
    // C: prefetch tile t+1 (flies during D)
    if (t < c) {
      const size_t kb_ = hS + (size_t)(t + 1) * 64;
      GLL16(Kh + (kb_ + krow0) * HD + kc0, &Ks[cur ^ 1][w * 512]);
      GLL16(Kh + (kb_ + krow1) * HD + kc1, &Ks[cur ^ 1][2048 + w * 512]);
      va = *(const short8*)(Vsrc + (size_t)(t + 1) * 64 * HD);
      vb = *(const short8*)(Vsrc + (size_t)(t + 1) * 64 * HD + HD);
    }
    // D: compute tile t
    f32x4 s[4] = {};
    __builtin_amdgcn_s_setprio(1);
#pragma unroll
    for (int kb = 0; kb < 4; ++kb) {
      int row = kb * 16 + l15;
      short8 k0 = *(const short8*)&Ks[cur][row * 64 + ((g ^ (row & 7)) << 3)];
      short8 k1 = *(const short8*)&Ks[cur][row * 64 + (((4 + g) ^ (row & 7)) << 3)];
      s[kb] = mfma16(k0, qf0, s[kb]);
      s[kb] = mfma16(k1, qf1, s[kb]);
    }
    __builtin_amdgcn_s_setprio(0);
    if (t == c) {  // diagonal: causal mask (q = l15 col, kv = row)
      const int kv0 = t * 64;
      int q = qr0 + l15;
#pragma unroll
      for (int kb = 0; kb < 4; ++kb) {
        int kvb = kv0 + kb * 16 + g * 4;
#pragma unroll
        for (int r = 0; r < 4; ++r)
          if (kvb + r > q) s[kb][r] = -1.0e30f;
      }
    }
    // in-register online softmax (q = l15, kv register-local)
    float mx = fmaxf(fmaxf(fmaxf(s[0][0], s[0][1]), fmaxf(s[0][2], s[0][3])),
                     fmaxf(fmaxf(fmaxf(s[1][0], s[1][1]), fmaxf(s[1][2], s[1][3])),
                           fmaxf(fmaxf(fmaxf(s[2][0], s[2][1]), fmaxf(s[2][2], s[2][3])),
                                 fmaxf(fmaxf(s[3][0], s[3][1]), fmaxf(s[3][2], s[3][3])))));
    mx = fmaxf(mx, __shfl_xor(mx, 16));
    mx = fmaxf(mx, __shfl_xor(mx, 32));
    if (!__all(mx - m_ <= 8.0f)) {  // defer-max
      float nm = fmaxf(m_, mx);
      float sc = __expf(m_ - nm);
      m_ = nm;
      lg *= sc;
#pragma unroll
      for (int r = 0; r < 4; ++r) {
        float so = __shfl(sc, g * 4 + r);
        o[0][r] *= so; o[1][r] *= so; o[2][r] *= so; o[3][r] *= so;
      }
    }
    // P = exp(S - m) -> bf16 -> per-wave LDS tile
    {
      float ps = 0.f;
#pragma unroll
      for (int kb = 0; kb < 4; ++kb) {
        float p0 = __expf(s[kb][0] - m_);
        float p1 = __expf(s[kb][1] - m_);
        float p2 = __expf(s[kb][2] - m_);
        float p3 = __expf(s[kb][3] - m_);
        ps += (p0 + p1) + (p2 + p3);
        unsigned w0, w1;
        asm("v_cvt_pk_bf16_f32 %0, %1, %2" : "=v"(w0) : "v"(p0), "v"(p1));
        asm("v_cvt_pk_bf16_f32 %0, %1, %2" : "=v"(w1) : "v"(p2), "v"(p3));
        int ch = (kb * 2 + (g >> 1)) ^ (l15 & 7);
        *(u32x2*)&Ps[w][l15 * 64 + ch * 8 + (g & 1) * 4] = (u32x2){w0, w1};
      }
      lg += ps;
    }
    // PV: O[16q][64d] += P * V
    short8 pa0 = *(const short8*)&Ps[w][l15 * 64 + ((g ^ (l15 & 7)) << 3)];
    short8 pa1 = *(const short8*)&Ps[w][l15 * 64 + (((4 + g) ^ (l15 & 7)) << 3)];
    __builtin_amdgcn_s_setprio(1);
#pragma unroll
    for (int nb = 0; nb < 4; ++nb) {
      int rv = nb * 16 + l15;
      int swv = (rv ^ (rv >> 3)) & 7;
      short8 v0f = *(const short8*)&Vt[cur][rv * 64 + ((g ^ swv) << 3)];
      short8 v1f = *(const short8*)&Vt[cur][rv * 64 + (((4 + g) ^ swv) << 3)];
      o[nb] = mfma16(pa0, v0f, o[nb]);
      o[nb] = mfma16(pa1, v1f, o[nb]);
    }
    __builtin_amdgcn_s_setprio(0);
  }

  // epilogue
  float l = lg;
  l += __shfl_xor(l, 16);
  l += __shfl_xor(l, 32);
  float il = 1.0f / l;
#pragma unroll
  for (int r = 0; r < 4; ++r) {
    float ilr = __shfl(il, g * 4 + r);
    int qrow = qr0 + g * 4 + r;
#pragma unroll
    for (int nb = 0; nb < 4; ++nb)
      Ob[(size_t)qrow * DIMM + h * HD + nb * 16 + l15] = f2b(o[nb][r] * ilr);
  }
}

// ---------------- workspace layout (bytes) --------------------------------------
#define OFF_XB 0u           // 8MB
#define OFF_WQKV 8388608u   // 6MB (wq,wk,wv bf16 contiguous)
#define OFF_WOB 14680064u   // 2MB
#define OFF_TAB 16777216u   // 2MB (float2[4096*64])
#define OFF_QH 18874368u    // 8MB
#define OFF_KH 27262976u    // 8MB
#define OFF_VH 35651584u    // 8MB
#define OFF_OB 44040192u    // 8MB -> end 50.3MB

extern "C" void kernel_launch(void* const* d_in, const int* in_sizes, int n_in,
                              void* d_out, int out_size, void* d_ws, size_t ws_size,
                              hipStream_t stream) {
  const float* x = (const float*)d_in[0];
  const float* Wq = (const float*)d_in[1];
  const float* Wk = (const float*)d_in[2];
  const float* Wv = (const float*)d_in[3];
  const float* Wo = (const float*)d_in[4];
  float* out = (float*)d_out;
  char* ws = (char*)d_ws;

  u16* xb = (u16*)(ws + OFF_XB);
  u16* wqkv = (u16*)(ws + OFF_WQKV);
  u16* wqb = wqkv;
  u16* wkb = wqkv + (size_t)DIMM * DIMM;
  u16* wvb = wqkv + (size_t)2 * DIMM * DIMM;
  u16* wob = (u16*)(ws + OFF_WOB);
  float2* tab = (float2*)(ws + OFF_TAB);
  u16* Qh = (u16*)(ws + OFF_QH);
  u16* Kh = (u16*)(ws + OFF_KH);
  u16* Vh = (u16*)(ws + OFF_VH);
  u16* Ob = (u16*)(ws + OFF_OB);

  cvt_all<<<9216, 256, 0, stream>>>(x, Wq, Wk, Wv, Wo, xb, wqb, wkb, wvb, wob, tab);

  gemm_bt<1><<<dim3(SEQ / 128, 3072 / 128), 256, 0, stream>>>(
      xb, wqkv, nullptr, tab, Qh, Kh, Vh, DIMM, 3072);

  attn_fwd<<<1024, 256, 0, stream>>>(Qh, Kh, Vh, Ob);

  gemm_bt<0><<<dim3(SEQ / 128, DIMM / 128), 256, 0, stream>>>(
      Ob, wob, out, nullptr, nullptr, nullptr, nullptr, DIMM, DIMM);
}

// Round 6
// 231.005 us; speedup vs baseline: 1.1166x; 1.1135x over previous
//
#include <hip/hip_runtime.h>

// MHA forward: x[4096,1024] fp32, W{q,k,v,o}[1024,1024] fp32 -> out[4096,1024] fp32
// cvt->bf16 + rope-table | fused QKV gemm w/ rope epilogue | flash attn
// (swapped-QK^T, flash-decode split for heavy chunks, LPT dispatch) | merge | O-proj

typedef __attribute__((ext_vector_type(4))) float f32x4;
typedef __attribute__((ext_vector_type(8))) short short8;
typedef __attribute__((ext_vector_type(2))) unsigned int u32x2;
typedef unsigned short u16;

#define SEQ 4096
#define DIMM 1024
#define NH 16
#define HD 64

__device__ __forceinline__ u16 f2b(float f) {
  unsigned u = __float_as_uint(f);
  u += 0x7FFFu + ((u >> 16) & 1u);
  return (u16)(u >> 16);
}
__device__ __forceinline__ f32x4 mfma16(short8 a, short8 b, f32x4 c) {
  return __builtin_amdgcn_mfma_f32_16x16x32_bf16(a, b, c, 0, 0, 0);
}
#define GLL16(gp, lp)                                                        \
  __builtin_amdgcn_global_load_lds(                                          \
      (const __attribute__((address_space(1))) unsigned int*)(gp),           \
      (__attribute__((address_space(3))) unsigned int*)(lp), 16, 0, 0)

// ---------------- convert x + 4 weights to bf16; build rope table ---------------
__global__ __launch_bounds__(256) void cvt_all(
    const float* __restrict__ x, const float* __restrict__ wq,
    const float* __restrict__ wk, const float* __restrict__ wv,
    const float* __restrict__ wo,
    u16* __restrict__ xb, u16* __restrict__ wqb, u16* __restrict__ wkb,
    u16* __restrict__ wvb, u16* __restrict__ wob, float2* __restrict__ tab) {
  int i = blockIdx.x * 256 + threadIdx.x;
  if (i < 2097152) {
    const float* src;
    u16* dst;
    int j;
    if (i < 1048576) {
      src = x; dst = xb; j = i;
    } else {
      int t = i - 1048576;
      int wsel = t >> 18;
      j = t & 262143;
      src = (wsel == 0) ? wq : (wsel == 1) ? wk : (wsel == 2) ? wv : wo;
      dst = (wsel == 0) ? wqb : (wsel == 1) ? wkb : (wsel == 2) ? wvb : wob;
    }
    float4 v = ((const float4*)src)[j];
    ushort4 o;
    o.x = f2b(v.x); o.y = f2b(v.y); o.z = f2b(v.z); o.w = f2b(v.w);
    ((ushort4*)dst)[j] = o;
  } else {
    int j = i - 2097152;  // 0..262143 = 4096*64
    int s = j >> 6, d = j & 63, fi = d >> 1;
    float ang = (float)s * powf(10000.0f, -(float)fi * (1.0f / 32.0f));
    float sn, cs;
    sincosf(ang, &sn, &cs);
    tab[j] = make_float2(cs, (d & 1) ? sn : -sn);
  }
}

// ---------------- QKV GEMM: [4096,1024] x [3072,1024]^T + rope + head scatter ---
__global__ __launch_bounds__(256) void gemm_qkv(
    const u16* __restrict__ A, const u16* __restrict__ B,
    const float2* __restrict__ tab, u16* __restrict__ Qh, u16* __restrict__ Kh,
    u16* __restrict__ Vh) {
  const int K = DIMM;
  __shared__ __align__(16) u16 As[2][4096];
  __shared__ __align__(16) u16 Bs[2][4096];
  const int tid = threadIdx.x;
  const int bm = blockIdx.x, bn = blockIdx.y;
  const int w = tid >> 6, lane = tid & 63;
  const int wm = w >> 1, wn = w & 1;
  const int l15 = lane & 15, g = lane >> 4;

  f32x4 acc[4][4] = {};

  const u16* Ap0 = A + (size_t)(bm * 128 + (tid >> 2)) * K + (tid & 3) * 8;
  const u16* Ap1 = Ap0 + (size_t)64 * K;
  const u16* Bp0 = B + (size_t)(bn * 128 + (tid >> 2)) * K + (tid & 3) * 8;
  const u16* Bp1 = Bp0 + (size_t)64 * K;

  GLL16(Ap0, &As[0][w * 512]);
  GLL16(Ap1, &As[0][2048 + w * 512]);
  GLL16(Bp0, &Bs[0][w * 512]);
  GLL16(Bp1, &Bs[0][2048 + w * 512]);
  __syncthreads();

  const int nk = K >> 5;
  for (int t = 0; t < nk; ++t) {
    const int cur = t & 1;
    if (t + 1 < nk) {
      const int k1 = (t + 1) * 32;
      GLL16(Ap0 + k1, &As[cur ^ 1][w * 512]);
      GLL16(Ap1 + k1, &As[cur ^ 1][2048 + w * 512]);
      GLL16(Bp0 + k1, &Bs[cur ^ 1][w * 512]);
      GLL16(Bp1 + k1, &Bs[cur ^ 1][2048 + w * 512]);
    }
    short8 af[4], bf[4];
#pragma unroll
    for (int m = 0; m < 4; ++m)
      af[m] = *(const short8*)&As[cur][(wm * 64 + m * 16 + l15) * 32 + g * 8];
#pragma unroll
    for (int n = 0; n < 4; ++n)
      bf[n] = *(const short8*)&Bs[cur][(wn * 64 + n * 16 + l15) * 32 + g * 8];
#pragma unroll
    for (int m = 0; m < 4; ++m)
#pragma unroll
      for (int n = 0; n < 4; ++n)
        acc[m][n] = mfma16(af[m], bf[n], acc[m][n]);
    __syncthreads();
  }

  // epilogue: bn 0..7 -> Q (rope, x0.125), 8..15 -> K (rope), 16..23 -> V
  const int sector = bn >> 3;
  const int hh = (bn & 7) * 2 + wn;
  u16* dst = (sector == 0) ? Qh : (sector == 1) ? Kh : Vh;
  const float qs = (sector == 0) ? 0.125f : 1.0f;
  const int evenlane = !(l15 & 1);
  const int dd0 = (l15 & ~1);
#pragma unroll
  for (int m = 0; m < 4; ++m) {
    const int sb = bm * 128 + wm * 64 + m * 16 + g * 4;
#pragma unroll
    for (int n = 0; n < 4; ++n) {
      const int d = n * 16 + l15;
      float val[4];
#pragma unroll
      for (int r = 0; r < 4; ++r) {
        float v = acc[m][n][r];
        if (sector < 2) {
          float p = __shfl_xor(v, 1);
          float2 tc = tab[(sb + r) * 64 + d];
          val[r] = (v * tc.x + p * tc.y) * qs;
        } else {
          val[r] = v;
        }
      }
      float x0 = __shfl_xor(val[0], 1);
      float x1 = __shfl_xor(val[1], 1);
      float x2 = __shfl_xor(val[2], 1);
      float x3 = __shfl_xor(val[3], 1);
      float aLo = evenlane ? val[0] : x2;
      float aHi = evenlane ? x0 : val[2];
      float bLo = evenlane ? val[1] : x3;
      float bHi = evenlane ? x1 : val[3];
      unsigned pkA, pkB;
      asm("v_cvt_pk_bf16_f32 %0, %1, %2" : "=v"(pkA) : "v"(aLo), "v"(aHi));
      asm("v_cvt_pk_bf16_f32 %0, %1, %2" : "=v"(pkB) : "v"(bLo), "v"(bHi));
      const int rA = evenlane ? 0 : 2, rB = evenlane ? 1 : 3;
      const int dcol = n * 16 + dd0;
      *(unsigned*)&dst[((size_t)hh * SEQ + sb + rA) * HD + dcol] = pkA;
      *(unsigned*)&dst[((size_t)hh * SEQ + sb + rB) * HD + dcol] = pkB;
    }
  }
}

// ---------------- O-proj GEMM: [4096,1024] x [1024,1024]^T, 128x64 tiles --------
__global__ __launch_bounds__(256) void gemm_o(
    const u16* __restrict__ A, const u16* __restrict__ B, float* __restrict__ C) {
  const int K = DIMM;
  __shared__ __align__(16) u16 As[2][4096];
  __shared__ __align__(16) u16 Bs[2][2048];
  const int tid = threadIdx.x;
  const int bm = blockIdx.x, bn = blockIdx.y;  // 32 x 16
  const int w = tid >> 6, lane = tid & 63;
  const int wm = w >> 1, wn = w & 1;
  const int l15 = lane & 15, g = lane >> 4;

  f32x4 acc[4][2] = {};

  const u16* Ap0 = A + (size_t)(bm * 128 + (tid >> 2)) * K + (tid & 3) * 8;
  const u16* Ap1 = Ap0 + (size_t)64 * K;
  const u16* Bp0 = B + (size_t)(bn * 64 + (tid >> 2)) * K + (tid & 3) * 8;

  GLL16(Ap0, &As[0][w * 512]);
  GLL16(Ap1, &As[0][2048 + w * 512]);
  GLL16(Bp0, &Bs[0][w * 512]);
  __syncthreads();

  const int nk = K >> 5;
  for (int t = 0; t < nk; ++t) {
    const int cur = t & 1;
    if (t + 1 < nk) {
      const int k1 = (t + 1) * 32;
      GLL16(Ap0 + k1, &As[cur ^ 1][w * 512]);
      GLL16(Ap1 + k1, &As[cur ^ 1][2048 + w * 512]);
      GLL16(Bp0 + k1, &Bs[cur ^ 1][w * 512]);
    }
    short8 af[4], bf[2];
#pragma unroll
    for (int m = 0; m < 4; ++m)
      af[m] = *(const short8*)&As[cur][(wm * 64 + m * 16 + l15) * 32 + g * 8];
#pragma unroll
    for (int n = 0; n < 2; ++n)
      bf[n] = *(const short8*)&Bs[cur][(wn * 32 + n * 16 + l15) * 32 + g * 8];
#pragma unroll
    for (int m = 0; m < 4; ++m)
#pragma unroll
      for (int n = 0; n < 2; ++n)
        acc[m][n] = mfma16(af[m], bf[n], acc[m][n]);
    __syncthreads();
  }

#pragma unroll
  for (int m = 0; m < 4; ++m) {
    int grow = bm * 128 + wm * 64 + m * 16 + g * 4;
#pragma unroll
    for (int n = 0; n < 2; ++n) {
      int gcol = bn * 64 + wn * 32 + n * 16 + l15;
#pragma unroll
      for (int r = 0; r < 4; ++r)
        C[(size_t)(grow + r) * DIMM + gcol] = acc[m][n][r];
    }
  }
}

// ---------------- causal flash attention (flash-decode split) -------------------
// 1536 blocks; head = L&15 (pins head to XCD h&7), u = L>>4 in [0,96) LPT-ordered:
// u<80: i=u/5,j=u%5; j<4 -> heavy chunk c=63-2i-(j>>1), half=j&1 (c>=32, KV split
// in two); j==4 -> light c=31-i. u>=80: light c=15-(u-80). Lights write Ob direct;
// heavies write f32 partials (O,m,l) merged by attn_merge.
__global__ __launch_bounds__(256, 4) void attn_fwd(
    const u16* __restrict__ Qh, const u16* __restrict__ Kh,
    const u16* __restrict__ Vh, u16* __restrict__ Ob,
    float* __restrict__ Opart, float2* __restrict__ ml) {
  __shared__ __align__(16) u16 Ks[2][64 * 64];   // [kv][d], chunk^=(row&7)
  __shared__ __align__(16) u16 Vt[2][64 * 64];   // [d][kv], chunk^=((d^(d>>3))&7)
  __shared__ __align__(16) u16 Ps[4][16 * 64];   // per-wave [q][kv], chunk^=(q&7)

  const int L = blockIdx.x;
  const int h = L & 15;
  const int u = L >> 4;
  int c, t0, t1, half = 0;
  if (u < 80) {
    int i = u / 5, j = u % 5;
    if (j < 4) {
      c = 63 - 2 * i - (j >> 1);
      half = j & 1;
      int mid = (c + 2) >> 1;
      t0 = half ? mid : 0;
      t1 = half ? (c + 1) : mid;
    } else {
      c = 31 - i; t0 = 0; t1 = c + 1;
    }
  } else {
    c = 15 - (u - 80); t0 = 0; t1 = c + 1;
  }
  const int heavy = (c >= 32);
  const int nt = t1 - t0;

  const int tid = threadIdx.x, w = tid >> 6, lane = tid & 63;
  const int l15 = lane & 15, g = lane >> 4;
  const int qr0 = c * 64 + w * 16;
  const size_t hS = (size_t)h * SEQ;

  const int krow0 = w * 8 + (lane >> 3);
  const int kc0 = ((lane & 7) ^ (krow0 & 7)) * 8;
  const int krow1 = 32 + krow0;
  const int kc1 = ((lane & 7) ^ (krow1 & 7)) * 8;
  const int kvp = tid >> 3, d0 = (tid & 7) * 8;
  const u16* Vsrc = Vh + (hS + kvp * 2) * HD + d0;
  int voff[8];
#pragma unroll
  for (int j = 0; j < 8; ++j) {
    int d = d0 + j;
    int sw = (d ^ (d >> 3)) & 7;
    voff[j] = d * 64 + (((kvp >> 2) ^ sw) << 3) + (kvp & 3) * 2;
  }

  const u16* Qp = Qh + (hS + qr0 + l15) * HD + g * 8;
  short8 qf0 = *(const short8*)(Qp);
  short8 qf1 = *(const short8*)(Qp + 32);

  f32x4 o[4] = {};
  float m_ = -3.0e38f, lg = 0.f;

  // prologue: stage tile t0
  GLL16(Kh + (hS + (size_t)t0 * 64 + krow0) * HD + kc0, &Ks[0][w * 512]);
  GLL16(Kh + (hS + (size_t)t0 * 64 + krow1) * HD + kc1, &Ks[0][2048 + w * 512]);
  short8 va = *(const short8*)(Vsrc + (size_t)t0 * 64 * HD);
  short8 vb = *(const short8*)(Vsrc + (size_t)t0 * 64 * HD + HD);

  for (int tt = 0; tt < nt; ++tt) {
    const int t = t0 + tt;
    const int cur = tt & 1;
    // A: write V(t) into Vt[cur]
    {
      u16* vtb = &Vt[cur][0];
#pragma unroll
      for (int j = 0; j < 8; ++j) {
        ushort2 pr;
        pr.x = (u16)va[j];
        pr.y = (u16)vb[j];
        *(ushort2*)(vtb + voff[j]) = pr;
      }
    }
    // B: the one barrier
    __syncthreads();
    // C: prefetch tile t+1
    if (tt + 1 < nt) {
      const size_t kb_ = hS + (size_t)(t + 1) * 64;
      GLL16(Kh + (kb_ + krow0) * HD + kc0, &Ks[cur ^ 1][w * 512]);
      GLL16(Kh + (kb_ + krow1) * HD + kc1, &Ks[cur ^ 1][2048 + w * 512]);
      va = *(const short8*)(Vsrc + (size_t)(t + 1) * 64 * HD);
      vb = *(const short8*)(Vsrc + (size_t)(t + 1) * 64 * HD + HD);
    }
    // D: compute tile t (swapped QK^T: q = l15, kv register-local)
    f32x4 s[4] = {};
    __builtin_amdgcn_s_setprio(1);
#pragma unroll
    for (int kb = 0; kb < 4; ++kb) {
      int row = kb * 16 + l15;
      short8 k0 = *(const short8*)&Ks[cur][row * 64 + ((g ^ (row & 7)) << 3)];
      short8 k1 = *(const short8*)&Ks[cur][row * 64 + (((4 + g) ^ (row & 7)) << 3)];
      s[kb] = mfma16(k0, qf0, s[kb]);
      s[kb] = mfma16(k1, qf1, s[kb]);
    }
    __builtin_amdgcn_s_setprio(0);
    if (t == c) {  // diagonal: causal mask
      const int kv0 = t * 64;
      int q = qr0 + l15;
#pragma unroll
      for (int kb = 0; kb < 4; ++kb) {
        int kvb = kv0 + kb * 16 + g * 4;
#pragma unroll
        for (int r = 0; r < 4; ++r)
          if (kvb + r > q) s[kb][r] = -1.0e30f;
      }
    }
    float mx = fmaxf(fmaxf(fmaxf(s[0][0], s[0][1]), fmaxf(s[0][2], s[0][3])),
                     fmaxf(fmaxf(fmaxf(s[1][0], s[1][1]), fmaxf(s[1][2], s[1][3])),
                           fmaxf(fmaxf(fmaxf(s[2][0], s[2][1]), fmaxf(s[2][2], s[2][3])),
                                 fmaxf(fmaxf(s[3][0], s[3][1]), fmaxf(s[3][2], s[3][3])))));
    mx = fmaxf(mx, __shfl_xor(mx, 16));
    mx = fmaxf(mx, __shfl_xor(mx, 32));
    if (!__all(mx - m_ <= 8.0f)) {  // defer-max
      float nm = fmaxf(m_, mx);
      float sc = __expf(m_ - nm);
      m_ = nm;
      lg *= sc;
#pragma unroll
      for (int r = 0; r < 4; ++r) {
        float so = __shfl(sc, g * 4 + r);
        o[0][r] *= so; o[1][r] *= so; o[2][r] *= so; o[3][r] *= so;
      }
    }
    {
      float ps = 0.f;
#pragma unroll
      for (int kb = 0; kb < 4; ++kb) {
        float p0 = __expf(s[kb][0] - m_);
        float p1 = __expf(s[kb][1] - m_);
        float p2 = __expf(s[kb][2] - m_);
        float p3 = __expf(s[kb][3] - m_);
        ps += (p0 + p1) + (p2 + p3);
        unsigned w0, w1;
        asm("v_cvt_pk_bf16_f32 %0, %1, %2" : "=v"(w0) : "v"(p0), "v"(p1));
        asm("v_cvt_pk_bf16_f32 %0, %1, %2" : "=v"(w1) : "v"(p2), "v"(p3));
        int ch = (kb * 2 + (g >> 1)) ^ (l15 & 7);
        *(u32x2*)&Ps[w][l15 * 64 + ch * 8 + (g & 1) * 4] = (u32x2){w0, w1};
      }
      lg += ps;
    }
    short8 pa0 = *(const short8*)&Ps[w][l15 * 64 + ((g ^ (l15 & 7)) << 3)];
    short8 pa1 = *(const short8*)&Ps[w][l15 * 64 + (((4 + g) ^ (l15 & 7)) << 3)];
    __builtin_amdgcn_s_setprio(1);
#pragma unroll
    for (int nb = 0; nb < 4; ++nb) {
      int rv = nb * 16 + l15;
      int swv = (rv ^ (rv >> 3)) & 7;
      short8 v0f = *(const short8*)&Vt[cur][rv * 64 + ((g ^ swv) << 3)];
      short8 v1f = *(const short8*)&Vt[cur][rv * 64 + (((4 + g) ^ swv) << 3)];
      o[nb] = mfma16(pa0, v0f, o[nb]);
      o[nb] = mfma16(pa1, v1f, o[nb]);
    }
    __builtin_amdgcn_s_setprio(0);
  }

  // epilogue
  float l = lg;
  l += __shfl_xor(l, 16);
  l += __shfl_xor(l, 32);
  if (heavy) {
    const int p = (h * 32 + (c - 32)) * 2 + half;
    if (lane < 16)
      ml[p * 64 + w * 16 + l15] = make_float2(m_, l);
    float* Od = Opart + ((size_t)p << 12);
#pragma unroll
    for (int nb = 0; nb < 4; ++nb)
#pragma unroll
      for (int r = 0; r < 4; ++r)
        Od[(w * 16 + g * 4 + r) * 64 + nb * 16 + l15] = o[nb][r];
  } else {
    float il = 1.0f / l;
#pragma unroll
    for (int r = 0; r < 4; ++r) {
      float ilr = __shfl(il, g * 4 + r);
      int qrow = qr0 + g * 4 + r;
#pragma unroll
      for (int nb = 0; nb < 4; ++nb)
        Ob[(size_t)qrow * DIMM + h * HD + nb * 16 + l15] = f2b(o[nb][r] * ilr);
    }
  }
}

// ---------------- merge heavy-chunk halves --------------------------------------
__global__ __launch_bounds__(256) void attn_merge(
    const float* __restrict__ Opart, const float2* __restrict__ ml,
    u16* __restrict__ Ob) {
  const int slot = blockIdx.x;  // 0..511 = h*32 + (c-32)
  const int h = slot >> 5;
  const int c = 32 + (slot & 31);
  const int t = threadIdx.x;
  const int q = t >> 2, dq = (t & 3) << 4;
  const int pA = slot * 2, pB = pA + 1;
  float2 a = ml[pA * 64 + q], b = ml[pB * 64 + q];
  float m = fmaxf(a.x, b.x);
  float fA = __expf(a.x - m), fB = __expf(b.x - m);
  float il = 1.0f / (a.y * fA + b.y * fB);
  const float* OA = Opart + ((size_t)pA << 12) + q * 64 + dq;
  const float* OB = Opart + ((size_t)pB << 12) + q * 64 + dq;
  u16* dst = Ob + (size_t)(c * 64 + q) * DIMM + h * HD + dq;
#pragma unroll
  for (int jj = 0; jj < 16; jj += 4) {
    float4 va = *(const float4*)(OA + jj);
    float4 vb = *(const float4*)(OB + jj);
    ushort4 o4;
    o4.x = f2b((va.x * fA + vb.x * fB) * il);
    o4.y = f2b((va.y * fA + vb.y * fB) * il);
    o4.z = f2b((va.z * fA + vb.z * fB) * il);
    o4.w = f2b((va.w * fA + vb.w * fB) * il);
    *(ushort4*)(dst + jj) = o4;
  }
}

// ---------------- workspace layout (bytes) --------------------------------------
#define OFF_XB 0u           // 8MB
#define OFF_WQKV 8388608u   // 6MB (wq,wk,wv bf16 contiguous)
#define OFF_WOB 14680064u   // 2MB
#define OFF_TAB 16777216u   // 2MB (float2[4096*64])
#define OFF_QH 18874368u    // 8MB
#define OFF_KH 27262976u    // 8MB
#define OFF_VH 35651584u    // 8MB
#define OFF_OB 44040192u    // 8MB
#define OFF_OPART 52428800u // 16MB (f32[1024][64][64])
#define OFF_ML 69206016u    // 512KB (float2[1024][64]) -> end 69.7MB

extern "C" void kernel_launch(void* const* d_in, const int* in_sizes, int n_in,
                              void* d_out, int out_size, void* d_ws, size_t ws_size,
                              hipStream_t stream) {
  const float* x = (const float*)d_in[0];
  const float* Wq = (const float*)d_in[1];
  const float* Wk = (const float*)d_in[2];
  const float* Wv = (const float*)d_in[3];
  const float* Wo = (const float*)d_in[4];
  float* out = (float*)d_out;
  char* ws = (char*)d_ws;

  u16* xb = (u16*)(ws + OFF_XB);
  u16* wqkv = (u16*)(ws + OFF_WQKV);
  u16* wqb = wqkv;
  u16* wkb = wqkv + (size_t)DIMM * DIMM;
  u16* wvb = wqkv + (size_t)2 * DIMM * DIMM;
  u16* wob = (u16*)(ws + OFF_WOB);
  float2* tab = (float2*)(ws + OFF_TAB);
  u16* Qh = (u16*)(ws + OFF_QH);
  u16* Kh = (u16*)(ws + OFF_KH);
  u16* Vh = (u16*)(ws + OFF_VH);
  u16* Ob = (u16*)(ws + OFF_OB);
  float* Opart = (float*)(ws + OFF_OPART);
  float2* ml = (float2*)(ws + OFF_ML);

  cvt_all<<<9216, 256, 0, stream>>>(x, Wq, Wk, Wv, Wo, xb, wqb, wkb, wvb, wob, tab);

  gemm_qkv<<<dim3(32, 24), 256, 0, stream>>>(xb, wqkv, tab, Qh, Kh, Vh);

  attn_fwd<<<1536, 256, 0, stream>>>(Qh, Kh, Vh, Ob, Opart, ml);

  attn_merge<<<512, 256, 0, stream>>>(Opart, ml, Ob);

  gemm_o<<<dim3(32, 16), 256, 0, stream>>>(Ob, wob, out);
}